// Round 9
// baseline (398.548 us; speedup 1.0000x reference)
//
#include <hip/hip_runtime.h>
#include <math.h>
#include <stdint.h>

#define NT 32768
#define DM 1024
#define NC 4096
#define CD 256

#define X_F4 (DM/4)
#define W_F4 (CD/4)
#define Z_F4 (CD/4)
#define C_F4 (CD/4)

// fragment-ordered extended codebook: 128 tiles x 17 frag-KB
// addr(ct, f, lane) = ct*TILE_B + f*1024 + lane*16, lane = (hi<<5)|row
// f<16: data k-slice f*16 + hi*8 ..+8 of code ct*32+row
// f=16: hi=0 -> [-hn2_hi, -hn2_lo, 0...]; hi=1 -> zeros
#define TILE_B 17408

typedef __attribute__((ext_vector_type(8))) short bf16x8;
typedef __attribute__((ext_vector_type(4))) float floatx4;
typedef __attribute__((ext_vector_type(16))) float floatx16;

__device__ __forceinline__ unsigned short f2bf(float f) {
    union { float f; uint32_t u; } v; v.f = f;
    uint32_t u = v.u;
    u += 0x7FFFu + ((u >> 16) & 1u);   // RN-even
    return (unsigned short)(u >> 16);
}

__device__ __forceinline__ void gload_lds16(const void* g, void* l) {
    __builtin_amdgcn_global_load_lds(
        (const __attribute__((address_space(1))) void*)g,
        (__attribute__((address_space(3))) void*)l, 16, 0, 0);
}

// split x into hi (truncated bf16) + lo (RNE bf16 of exact f32 residual)
__device__ __forceinline__ void split8(const float4 f0, const float4 f1,
                                       bf16x8& h, bf16x8& l) {
    float f[8] = {f0.x, f0.y, f0.z, f0.w, f1.x, f1.y, f1.z, f1.w};
    #pragma unroll
    for (int j = 0; j < 8; ++j) {
        union { float f; uint32_t u; } v; v.f = f[j];
        h[j] = (short)(v.u >> 16);
        union { uint32_t u; float f; } t; t.u = v.u & 0xFFFF0000u;
        l[j] = (short)f2bf(f[j] - t.f);
    }
}

// ---------------------------------------------------------------------------
// K0: build fragment-ordered extended bf16 codebook (see layout above).
// ---------------------------------------------------------------------------
__global__ __launch_bounds__(256) void k0_prep(const float4* __restrict__ cb,
                                               ushort* __restrict__ cbb2) {
    int tid = threadIdx.x;
    int l = tid & 63, wid = tid >> 6;
    int code = blockIdx.x * 8 + wid * 2 + (l >> 5);
    int fr = l & 31, f = fr >> 1, hi = fr & 1;
    const float4* p = cb + (size_t)code * C_F4 + f * 4 + hi * 2;
    float4 f0 = p[0], f1 = p[1];
    bf16x8 h;
    h[0] = (short)f2bf(f0.x); h[1] = (short)f2bf(f0.y);
    h[2] = (short)f2bf(f0.z); h[3] = (short)f2bf(f0.w);
    h[4] = (short)f2bf(f1.x); h[5] = (short)f2bf(f1.y);
    h[6] = (short)f2bf(f1.z); h[7] = (short)f2bf(f1.w);
    float ss = f0.x*f0.x + f0.y*f0.y + f0.z*f0.z + f0.w*f0.w
             + f1.x*f1.x + f1.y*f1.y + f1.z*f1.z + f1.w*f1.w;
    #pragma unroll
    for (int m = 16; m >= 1; m >>= 1) ss += __shfl_xor(ss, m, 64);
    int ct = code >> 5, r = code & 31;
    char* base = (char*)cbb2 + (size_t)ct * TILE_B;
    *(bf16x8*)(base + f * 1024 + (((hi << 5) | r) << 4)) = h;
    if (fr == 0) {
        float nh = 2.0f - 0.5f * ss;                   // = -hn2
        union { float f; uint32_t u; } v; v.f = nh;
        uint32_t uh = v.u & 0xFFFF0000u;
        union { uint32_t u; float f; } t; t.u = uh;
        bf16x8 e = (bf16x8){0, 0, 0, 0, 0, 0, 0, 0};
        e[0] = (short)(uh >> 16);
        e[1] = (short)f2bf(nh - t.f);
        *(bf16x8*)(base + 16 * 1024 + (r << 4)) = e;
    } else if (fr == 1) {
        bf16x8 z = (bf16x8){0, 0, 0, 0, 0, 0, 0, 0};
        *(bf16x8*)(base + 16 * 1024 + ((32 | r) << 4)) = z;
    }
}

// ---------------------------------------------------------------------------
// K0b: W [1024][256] f32 -> transposed split-bf16 WT_hi/WT_lo [256][1024].
// ---------------------------------------------------------------------------
__global__ __launch_bounds__(256) void k0b_wsplit(const float4* __restrict__ W,
                                                  ushort* __restrict__ WTh,
                                                  ushort* __restrict__ WTl) {
    __shared__ float lds[16][260];
    int slab = blockIdx.x;              // 64 slabs of 16 k-rows
    int tid = threadIdx.x;
    #pragma unroll
    for (int jj = 0; jj < 4; ++jj) {
        int v = jj * 256 + tid;         // 0..1023
        int row = v >> 6, f4 = v & 63;
        float4 d = W[(size_t)(slab * 16 + row) * W_F4 + f4];
        *(float4*)&lds[row][f4 * 4] = d;
    }
    __syncthreads();
    int c = tid;                        // column (n) 0..255
    #pragma unroll
    for (int kb = 0; kb < 2; ++kb) {
        bf16x8 h, l;
        #pragma unroll
        for (int j = 0; j < 8; ++j) {
            float x = lds[kb * 8 + j][c];
            union { float f; uint32_t u; } v; v.f = x;
            h[j] = (short)(v.u >> 16);
            union { uint32_t u; float f; } t; t.u = v.u & 0xFFFF0000u;
            l[j] = (short)f2bf(x - t.f);
        }
        size_t off = (size_t)c * 1024 + slab * 16 + kb * 8;
        *(bf16x8*)(WTh + off) = h;
        *(bf16x8*)(WTl + off) = l;
    }
}

// ---------------------------------------------------------------------------
// K1: z_pre = x @ W_down via split-bf16 MFMA (Ootomo 3-term: hh + hl + lh).
// (unchanged — will surface in top-5 with counters once k2 drops)
// ---------------------------------------------------------------------------
__global__ __launch_bounds__(256, 2) void k1_gemm1(const float4* __restrict__ X,
                                                   const ushort* __restrict__ WTh,
                                                   const ushort* __restrict__ WTl,
                                                   float4* __restrict__ Zp) {
    __shared__ __align__(16) char lds[65536];
    char* Ah = lds;              // 128 rows x 64 bf16 (swizzled chunks)
    char* Al = lds + 16384;
    char* Bh = lds + 32768;      // 128 cols(n) x 64 bf16
    char* Bl = lds + 49152;

    int tid  = threadIdx.x;
    int w    = tid >> 6, lane = tid & 63;
    int wm   = w >> 1, wn = w & 1;
    int c    = lane & 15, q = lane >> 4;
    int mb   = blockIdx.x >> 1, nb = blockIdx.x & 1;
    int m0   = mb * 128;
    int n0   = nb * 128;

    auto issue_loads = [&](int kt, float4* ga, bf16x8* gbh, bf16x8* gbl) {
        #pragma unroll
        for (int jj = 0; jj < 4; ++jj) {
            int v = jj * 256 + tid;           // 0..1023
            int row = v >> 3, ch = v & 7;
            const float4* p = X + (size_t)(m0 + row) * X_F4 + kt * 16 + ch * 2;
            ga[jj * 2]     = p[0];
            ga[jj * 2 + 1] = p[1];
        }
        #pragma unroll
        for (int jj = 0; jj < 4; ++jj) {
            int v = jj * 256 + tid;
            int col = v >> 3, ch = v & 7;
            size_t off = (size_t)(n0 + col) * 1024 + kt * 64 + ch * 8;
            gbh[jj] = *(const bf16x8*)(WTh + off);
            gbl[jj] = *(const bf16x8*)(WTl + off);
        }
    };
    auto write_lds = [&](const float4* ga, const bf16x8* gbh, const bf16x8* gbl) {
        #pragma unroll
        for (int jj = 0; jj < 4; ++jj) {
            int v = jj * 256 + tid;
            int row = v >> 3, ch = v & 7;
            bf16x8 h, l;
            split8(ga[jj * 2], ga[jj * 2 + 1], h, l);
            int off = row * 128 + ((ch ^ (row & 7)) << 4);
            *(bf16x8*)(Ah + off) = h;
            *(bf16x8*)(Al + off) = l;
        }
        #pragma unroll
        for (int jj = 0; jj < 4; ++jj) {
            int v = jj * 256 + tid;
            int col = v >> 3, ch = v & 7;
            int off = col * 128 + ((ch ^ (col & 7)) << 4);
            *(bf16x8*)(Bh + off) = gbh[jj];
            *(bf16x8*)(Bl + off) = gbl[jj];
        }
    };

    floatx4 acc[4][4];
    #pragma unroll
    for (int i = 0; i < 4; ++i)
        #pragma unroll
        for (int j = 0; j < 4; ++j) acc[i][j] = (floatx4){0.f, 0.f, 0.f, 0.f};

    float4 ga[8]; bf16x8 gbh[4], gbl[4];
    issue_loads(0, ga, gbh, gbl);
    write_lds(ga, gbh, gbl);

    for (int kt = 0; kt < 16; ++kt) {
        __syncthreads();
        if (kt < 15) issue_loads(kt + 1, ga, gbh, gbl);

        #pragma unroll
        for (int ks = 0; ks < 2; ++ks) {
            bf16x8 xh[4], xl[4], wh[4], wl[4];
            #pragma unroll
            for (int i = 0; i < 4; ++i) {
                int xrow = wm * 64 + i * 16 + c;
                int xoff = xrow * 128 + (((ks * 4 + q) ^ (xrow & 7)) << 4);
                xh[i] = *(const bf16x8*)(Ah + xoff);
                xl[i] = *(const bf16x8*)(Al + xoff);
                int wrow = wn * 64 + i * 16 + c;
                int woff = wrow * 128 + (((ks * 4 + q) ^ (wrow & 7)) << 4);
                wh[i] = *(const bf16x8*)(Bh + woff);
                wl[i] = *(const bf16x8*)(Bl + woff);
            }
            #pragma unroll
            for (int xi = 0; xi < 4; ++xi)
                #pragma unroll
                for (int ni = 0; ni < 4; ++ni) {
                    acc[xi][ni] = __builtin_amdgcn_mfma_f32_16x16x32_bf16(wh[ni], xh[xi], acc[xi][ni], 0, 0, 0);
                    acc[xi][ni] = __builtin_amdgcn_mfma_f32_16x16x32_bf16(wh[ni], xl[xi], acc[xi][ni], 0, 0, 0);
                    acc[xi][ni] = __builtin_amdgcn_mfma_f32_16x16x32_bf16(wl[ni], xh[xi], acc[xi][ni], 0, 0, 0);
                }
        }

        __syncthreads();
        if (kt < 15) write_lds(ga, gbh, gbl);
    }

    #pragma unroll
    for (int xi = 0; xi < 4; ++xi) {
        int tok = m0 + wm * 64 + xi * 16 + c;
        #pragma unroll
        for (int ni = 0; ni < 4; ++ni) {
            int nf4 = nb * 32 + wn * 16 + ni * 4 + q;
            float4 o;
            o.x = acc[xi][ni][0]; o.y = acc[xi][ni][1];
            o.z = acc[xi][ni][2]; o.w = acc[xi][ni][3];
            Zp[(size_t)tok * Z_F4 + nf4] = o;
        }
    }
}

// ---------------------------------------------------------------------------
// K1b: z = (z_pre + b) / (||z_pre + b|| + 1e-6) (unchanged)
// ---------------------------------------------------------------------------
__global__ __launch_bounds__(256) void k1b_norm(float4* __restrict__ Z,
                                                const float4* __restrict__ bias) {
    int wid = threadIdx.x >> 6, lane = threadIdx.x & 63;
    int t = blockIdx.x * 4 + wid;
    float4 b = bias[lane];
    float4 z = Z[(size_t)t * Z_F4 + lane];
    z.x += b.x; z.y += b.y; z.z += b.z; z.w += b.w;
    double ss = (double)z.x*z.x + (double)z.y*z.y + (double)z.z*z.z + (double)z.w*z.w;
    #pragma unroll
    for (int m = 32; m >= 1; m >>= 1) ss += __shfl_xor(ss, m, 64);
    float inv = 1.0f / ((float)sqrt(ss) + 1e-6f);
    z.x *= inv; z.y *= inv; z.z *= inv; z.w *= inv;
    Z[(size_t)t * Z_F4 + lane] = z;
}

// ---------------------------------------------------------------------------
// K2 v5: LDS double-buffer + counted vmcnt (T3/T4 shape — pipeline lives in
// the memory counter, immune to regalloc). Block = 4 waves = 2 token groups
// (wm) x 2 code halves (wc); 64 tokens; grid 512 -> 2 blocks/CU.
// Each wc stream staged into LDS[2 bufs x 17408] via global_load_lds
// (fragment-ordered layout matches HW: uniform LDS base + lane*16, per-lane
// global src). wm=0 stages frags 0-8 (9 loads), wm=1 frags 9-16 (8).
// Loop: vmcnt(own L) -> s_barrier -> 17 ds_read_b128 + MFMA + med3 sort ->
// s_barrier -> issue stage t+2 (clamped dummies at tail keep counts
// uniform; never drains to 0). Both wm waves SHARE each tile: L2 stream
// halved to 1.14 GB (floor ~33 us).
// ---------------------------------------------------------------------------
__global__ __launch_bounds__(256, 2) void k2_mfma(const float* __restrict__ Z,
                                                  const ushort* __restrict__ Cbb2,
                                                  int4* __restrict__ cands) {
    __shared__ __align__(16) char sbuf[69632];   // [wc][2][17408]
    __shared__ uint32_t Mk[64][4][4];            // [token][wc*2+hi][rank]

    int tid  = threadIdx.x;
    int w    = tid >> 6;
    int wm   = w >> 1;           // token group / stage split
    int wc   = w & 1;            // code half
    int lane = tid & 63;
    int r    = lane & 31;
    int hi   = lane >> 5;
    int t0   = blockIdx.x * 64;

    // ---- resident token fragments (B-operand): col=r, k = f*16 + hi*8 + j
    bf16x8 Bt[17];
    #pragma unroll
    for (int f = 0; f < 16; ++f) {
        const float* zp = Z + (size_t)(t0 + wm * 32 + r) * CD + f * 16 + hi * 8;
        float4 f0 = *(const float4*)zp;
        float4 f1 = *(const float4*)(zp + 4);
        bf16x8 b;
        b[0] = (short)f2bf(f0.x); b[1] = (short)f2bf(f0.y);
        b[2] = (short)f2bf(f0.z); b[3] = (short)f2bf(f0.w);
        b[4] = (short)f2bf(f1.x); b[5] = (short)f2bf(f1.y);
        b[6] = (short)f2bf(f1.z); b[7] = (short)f2bf(f1.w);
        Bt[f] = b;
    }
    {
        bf16x8 b = (bf16x8){0, 0, 0, 0, 0, 0, 0, 0};
        if (hi == 0) { b[0] = (short)0x3F80; b[1] = (short)0x3F80; }  // 1.0,1.0
        Bt[16] = b;
    }

    char* myStream = sbuf + wc * 34816;

    // stage my fragment range of global tile gt into LDS buffer dst.
    // per-lane global src; LDS dest = uniform base + lane*16 (HW).
    // gt==0: bump row-0 lanes (code 0) to row 1 (code 1) — clamp.
    auto stage = [&](int gt, char* dst) {
        const char* tb = (const char*)Cbb2 + (size_t)gt * TILE_B;
        int lo = lane * 16;
        if (gt == 0 && (lane & 31) == 0) lo += 16;
        if (wm == 0) {
            #pragma unroll
            for (int f = 0; f < 9; ++f)
                gload_lds16(tb + f * 1024 + lo, dst + f * 1024);
        } else {
            #pragma unroll
            for (int f = 9; f < 17; ++f)
                gload_lds16(tb + f * 1024 + lo, dst + f * 1024);
        }
    };

    float K1f = 0.0f, K2f = 0.0f, K3f = 0.0f, K4f = 0.0f;

    auto computeT = [&](const char* sb, int ct) {
        floatx16 Cc;
        #pragma unroll
        for (int i = 0; i < 16; ++i) Cc[i] = 0.0f;
        #pragma unroll
        for (int f = 0; f < 17; ++f) {
            bf16x8 Af = *(const bf16x8*)(sb + f * 1024 + lane * 16);
            Cc = __builtin_amdgcn_mfma_f32_32x32x16_bf16(Af, Bt[f], Cc, 0, 0, 0);
        }
        #pragma unroll
        for (int reg = 0; reg < 16; ++reg) {
            union { float f; uint32_t u; } uv; uv.f = Cc[reg];
            uint32_t ku = (uv.u & 0xFFFFF800u) | ((uint32_t)ct << 4) | (uint32_t)reg;
            union { uint32_t u; float f; } kv; kv.u = ku;
            float k = kv.f;
            K4f = __builtin_amdgcn_fmed3f(K3f, K4f, k);
            K3f = __builtin_amdgcn_fmed3f(K2f, K3f, k);
            K2f = __builtin_amdgcn_fmed3f(K1f, K2f, k);
            K1f = fmaxf(K1f, k);
        }
    };

    // prologue: stage tiles 0,1 of my stream
    stage(wc * 64 + 0, myStream);
    stage(wc * 64 + 1, myStream + 17408);

    for (int ctl = 0; ctl < 64; ++ctl) {
        // wait own oldest stage (tile ctl) complete; partner covered by its
        // own wait + the barrier. Counts uniform (dummy stages at tail).
        if (wm == 0) { asm volatile("s_waitcnt vmcnt(9)" ::: "memory"); }
        else         { asm volatile("s_waitcnt vmcnt(8)" ::: "memory"); }
        __builtin_amdgcn_s_barrier();

        computeT(myStream + (ctl & 1) * 17408, wc * 64 + ctl);

        __builtin_amdgcn_s_barrier();
        // refill the buffer just consumed with tile ctl+2 (clamped -> dummy)
        stage(wc * 64 + ((ctl + 2) & 63), myStream + (ctl & 1) * 17408);
    }

    // ---- merge: per token 4 sources (wc x hi) x top-4 -> global top-4
    {
        int lt = wm * 32 + r, src = wc * 2 + hi;
        union { float f; uint32_t u; } a, b, c, d;
        a.f = K1f; b.f = K2f; c.f = K3f; d.f = K4f;
        Mk[lt][src][0] = a.u; Mk[lt][src][1] = b.u;
        Mk[lt][src][2] = c.u; Mk[lt][src][3] = d.u;
    }
    __syncthreads();

    if (tid < 64) {
        uint32_t bk0 = 0, bk1 = 0, bk2 = 0, bk3 = 0;
        uint32_t be0 = 0, be1 = 0, be2 = 0, be3 = 0;
        #pragma unroll
        for (int s = 0; s < 4; ++s) {
            #pragma unroll
            for (int j = 0; j < 4; ++j) {
                uint32_t key = Mk[tid][s][j];
                uint32_t e = (uint32_t)s;           // hi = s&1
                if (key > bk0) {
                    bk3 = bk2; be3 = be2; bk2 = bk1; be2 = be1;
                    bk1 = bk0; be1 = be0; bk0 = key; be0 = e;
                } else if (key > bk1) {
                    bk3 = bk2; be3 = be2; bk2 = bk1; be2 = be1; bk1 = key; be1 = e;
                } else if (key > bk2) {
                    bk3 = bk2; be3 = be2; bk2 = key; be2 = e;
                } else if (key > bk3) {
                    bk3 = key; be3 = e;
                }
            }
        }
        auto dec = [&](uint32_t key, uint32_t e) -> int {
            int ct = (int)((key >> 4) & 127u);
            int rg = (int)(key & 15u);
            int row = (rg & 3) + 8 * (rg >> 2) + 4 * (int)(e & 1);
            int code = ct * 32 + row;
            return code < 1 ? 1 : code;
        };
        int4 out;
        out.x = dec(bk0, be0); out.y = dec(bk1, be1);
        out.z = dec(bk2, be2); out.w = dec(bk3, be3);
        cands[t0 + tid] = out;
    }
}

// ---------------------------------------------------------------------------
// K3: f64 re-rank of 4 candidates (code 0 invalid; ties -> lowest index),
// write index (as float) + gather hard code. One wave per token.
// ---------------------------------------------------------------------------
__global__ __launch_bounds__(256) void k3_refine(const float4* __restrict__ Z,
                                                 const float4* __restrict__ Cb,
                                                 const int4* __restrict__ cands,
                                                 float* __restrict__ idxOut,
                                                 float4* __restrict__ hardOut) {
    int wid = threadIdx.x >> 6, lane = threadIdx.x & 63;
    int t = blockIdx.x * 4 + wid;
    int4 cd = cands[t];
    int cc[4] = {cd.x, cd.y, cd.z, cd.w};
    float4 z = Z[(size_t)t * Z_F4 + lane];
    double best = -1.0e300;
    int bi = NC;   // sentinel
    #pragma unroll
    for (int e = 0; e < 4; ++e) {
        int idx = cc[e];
        float4 cf = Cb[(size_t)idx * C_F4 + lane];
        double dot = (double)z.x*cf.x + (double)z.y*cf.y + (double)z.z*cf.z + (double)z.w*cf.w;
        double nrm = (double)cf.x*cf.x + (double)cf.y*cf.y + (double)cf.z*cf.z + (double)cf.w*cf.w;
        #pragma unroll
        for (int m = 32; m >= 1; m >>= 1) {
            dot += __shfl_xor(dot, m, 64);
            nrm += __shfl_xor(nrm, m, 64);
        }
        double s = dot - 0.5 * nrm;
        if (idx >= 1 && (s > best || (s == best && idx < bi))) { best = s; bi = idx; }
    }
    if (lane == 0) idxOut[t] = (float)bi;
    hardOut[(size_t)t * C_F4 + lane] = Cb[(size_t)bi * C_F4 + lane];
}

// ---------------------------------------------------------------------------
extern "C" void kernel_launch(void* const* d_in, const int* in_sizes, int n_in,
                              void* d_out, int out_size, void* d_ws, size_t ws_size,
                              hipStream_t stream) {
    const float* x  = (const float*)d_in[0];   // 32768 x 1024
    const float* cb = (const float*)d_in[1];   // 4096 x 256
    const float* w  = (const float*)d_in[2];   // 1024 x 256
    const float* bd = (const float*)d_in[3];   // 256

    float* zOut    = (float*)d_out;                    // 32768 x 256
    float* idxOut  = zOut + (size_t)NT * CD;           // 32768 (as float values)
    float* hardOut = idxOut + NT;                      // 32768 x 256

    int4*   cands = (int4*)d_ws;                             // 512 KB
    ushort* cbb2  = (ushort*)((char*)d_ws + 524288);         // 128*17408 = 2,228,224 B
    ushort* wth   = (ushort*)((char*)d_ws + 2752512);        // 512 KB bf16 W^T hi
    ushort* wtl   = (ushort*)((char*)d_ws + 3276800);        // 512 KB bf16 W^T lo

    k0_prep<<<NC / 8, 256, 0, stream>>>((const float4*)cb, cbb2);
    k0b_wsplit<<<DM / 16, 256, 0, stream>>>((const float4*)w, wth, wtl);
    k1_gemm1<<<(NT / 128) * 2, 256, 0, stream>>>((const float4*)x, wth, wtl,
                                                 (float4*)zOut);
    k1b_norm<<<NT / 4, 256, 0, stream>>>((float4*)zOut, (const float4*)bd);
    k2_mfma<<<NT / 64, 256, 0, stream>>>(zOut, cbb2, cands);
    k3_refine<<<NT / 4, 256, 0, stream>>>((const float4*)zOut, (const float4*)cb,
                                          cands, idxOut, (float4*)hardOut);
}

// Round 10
// 390.769 us; speedup vs baseline: 1.0199x; 1.0199x over previous
//
#include <hip/hip_runtime.h>
#include <math.h>
#include <stdint.h>

#define NT 32768
#define DM 1024
#define NC 4096
#define CD 256

#define X_F4 (DM/4)
#define W_F4 (CD/4)
#define Z_F4 (CD/4)
#define C_F4 (CD/4)

// fragment-ordered extended codebook: 128 tiles x 17 frag-KB
// addr(ct, f, lane) = ct*TILE_B + f*1024 + lane*16, lane = (hi<<5)|row
// f<16: data k-slice f*16 + hi*8 ..+8 of code ct*32+row
// f=16: hi=0 -> [-hn2_hi, -hn2_lo, 0...]; hi=1 -> zeros
#define TILE_B 17408

typedef __attribute__((ext_vector_type(8))) short bf16x8;
typedef __attribute__((ext_vector_type(4))) float floatx4;
typedef __attribute__((ext_vector_type(16))) float floatx16;

__device__ __forceinline__ unsigned short f2bf(float f) {
    union { float f; uint32_t u; } v; v.f = f;
    uint32_t u = v.u;
    u += 0x7FFFu + ((u >> 16) & 1u);   // RN-even
    return (unsigned short)(u >> 16);
}

__device__ __forceinline__ void gload_lds16(const void* g, void* l) {
    __builtin_amdgcn_global_load_lds(
        (const __attribute__((address_space(1))) void*)g,
        (__attribute__((address_space(3))) void*)l, 16, 0, 0);
}

// split x into hi (truncated bf16) + lo (RNE bf16 of exact f32 residual)
__device__ __forceinline__ void split8(const float4 f0, const float4 f1,
                                       bf16x8& h, bf16x8& l) {
    float f[8] = {f0.x, f0.y, f0.z, f0.w, f1.x, f1.y, f1.z, f1.w};
    #pragma unroll
    for (int j = 0; j < 8; ++j) {
        union { float f; uint32_t u; } v; v.f = f[j];
        h[j] = (short)(v.u >> 16);
        union { uint32_t u; float f; } t; t.u = v.u & 0xFFFF0000u;
        l[j] = (short)f2bf(f[j] - t.f);
    }
}

// ---------------------------------------------------------------------------
// K0: build fragment-ordered extended bf16 codebook (see layout above).
// ---------------------------------------------------------------------------
__global__ __launch_bounds__(256) void k0_prep(const float4* __restrict__ cb,
                                               ushort* __restrict__ cbb2) {
    int tid = threadIdx.x;
    int l = tid & 63, wid = tid >> 6;
    int code = blockIdx.x * 8 + wid * 2 + (l >> 5);
    int fr = l & 31, f = fr >> 1, hi = fr & 1;
    const float4* p = cb + (size_t)code * C_F4 + f * 4 + hi * 2;
    float4 f0 = p[0], f1 = p[1];
    bf16x8 h;
    h[0] = (short)f2bf(f0.x); h[1] = (short)f2bf(f0.y);
    h[2] = (short)f2bf(f0.z); h[3] = (short)f2bf(f0.w);
    h[4] = (short)f2bf(f1.x); h[5] = (short)f2bf(f1.y);
    h[6] = (short)f2bf(f1.z); h[7] = (short)f2bf(f1.w);
    float ss = f0.x*f0.x + f0.y*f0.y + f0.z*f0.z + f0.w*f0.w
             + f1.x*f1.x + f1.y*f1.y + f1.z*f1.z + f1.w*f1.w;
    #pragma unroll
    for (int m = 16; m >= 1; m >>= 1) ss += __shfl_xor(ss, m, 64);
    int ct = code >> 5, r = code & 31;
    char* base = (char*)cbb2 + (size_t)ct * TILE_B;
    *(bf16x8*)(base + f * 1024 + (((hi << 5) | r) << 4)) = h;
    if (fr == 0) {
        float nh = 2.0f - 0.5f * ss;                   // = -hn2
        union { float f; uint32_t u; } v; v.f = nh;
        uint32_t uh = v.u & 0xFFFF0000u;
        union { uint32_t u; float f; } t; t.u = uh;
        bf16x8 e = (bf16x8){0, 0, 0, 0, 0, 0, 0, 0};
        e[0] = (short)(uh >> 16);
        e[1] = (short)f2bf(nh - t.f);
        *(bf16x8*)(base + 16 * 1024 + (r << 4)) = e;
    } else if (fr == 1) {
        bf16x8 z = (bf16x8){0, 0, 0, 0, 0, 0, 0, 0};
        *(bf16x8*)(base + 16 * 1024 + ((32 | r) << 4)) = z;
    }
}

// ---------------------------------------------------------------------------
// K0b: W [1024][256] f32 -> transposed split-bf16 WT_hi/WT_lo [256][1024].
// ---------------------------------------------------------------------------
__global__ __launch_bounds__(256) void k0b_wsplit(const float4* __restrict__ W,
                                                  ushort* __restrict__ WTh,
                                                  ushort* __restrict__ WTl) {
    __shared__ float lds[16][260];
    int slab = blockIdx.x;              // 64 slabs of 16 k-rows
    int tid = threadIdx.x;
    #pragma unroll
    for (int jj = 0; jj < 4; ++jj) {
        int v = jj * 256 + tid;         // 0..1023
        int row = v >> 6, f4 = v & 63;
        float4 d = W[(size_t)(slab * 16 + row) * W_F4 + f4];
        *(float4*)&lds[row][f4 * 4] = d;
    }
    __syncthreads();
    int c = tid;                        // column (n) 0..255
    #pragma unroll
    for (int kb = 0; kb < 2; ++kb) {
        bf16x8 h, l;
        #pragma unroll
        for (int j = 0; j < 8; ++j) {
            float x = lds[kb * 8 + j][c];
            union { float f; uint32_t u; } v; v.f = x;
            h[j] = (short)(v.u >> 16);
            union { uint32_t u; float f; } t; t.u = v.u & 0xFFFF0000u;
            l[j] = (short)f2bf(x - t.f);
        }
        size_t off = (size_t)c * 1024 + slab * 16 + kb * 8;
        *(bf16x8*)(WTh + off) = h;
        *(bf16x8*)(WTl + off) = l;
    }
}

// ---------------------------------------------------------------------------
// K1: z_pre = x @ W_down via split-bf16 MFMA (Ootomo 3-term: hh + hl + lh).
// ---------------------------------------------------------------------------
__global__ __launch_bounds__(256, 2) void k1_gemm1(const float4* __restrict__ X,
                                                   const ushort* __restrict__ WTh,
                                                   const ushort* __restrict__ WTl,
                                                   float4* __restrict__ Zp) {
    __shared__ __align__(16) char lds[65536];
    char* Ah = lds;              // 128 rows x 64 bf16 (swizzled chunks)
    char* Al = lds + 16384;
    char* Bh = lds + 32768;      // 128 cols(n) x 64 bf16
    char* Bl = lds + 49152;

    int tid  = threadIdx.x;
    int w    = tid >> 6, lane = tid & 63;
    int wm   = w >> 1, wn = w & 1;
    int c    = lane & 15, q = lane >> 4;
    int mb   = blockIdx.x >> 1, nb = blockIdx.x & 1;
    int m0   = mb * 128;
    int n0   = nb * 128;

    auto issue_loads = [&](int kt, float4* ga, bf16x8* gbh, bf16x8* gbl) {
        #pragma unroll
        for (int jj = 0; jj < 4; ++jj) {
            int v = jj * 256 + tid;           // 0..1023
            int row = v >> 3, ch = v & 7;
            const float4* p = X + (size_t)(m0 + row) * X_F4 + kt * 16 + ch * 2;
            ga[jj * 2]     = p[0];
            ga[jj * 2 + 1] = p[1];
        }
        #pragma unroll
        for (int jj = 0; jj < 4; ++jj) {
            int v = jj * 256 + tid;
            int col = v >> 3, ch = v & 7;
            size_t off = (size_t)(n0 + col) * 1024 + kt * 64 + ch * 8;
            gbh[jj] = *(const bf16x8*)(WTh + off);
            gbl[jj] = *(const bf16x8*)(WTl + off);
        }
    };
    auto write_lds = [&](const float4* ga, const bf16x8* gbh, const bf16x8* gbl) {
        #pragma unroll
        for (int jj = 0; jj < 4; ++jj) {
            int v = jj * 256 + tid;
            int row = v >> 3, ch = v & 7;
            bf16x8 h, l;
            split8(ga[jj * 2], ga[jj * 2 + 1], h, l);
            int off = row * 128 + ((ch ^ (row & 7)) << 4);
            *(bf16x8*)(Ah + off) = h;
            *(bf16x8*)(Al + off) = l;
        }
        #pragma unroll
        for (int jj = 0; jj < 4; ++jj) {
            int v = jj * 256 + tid;
            int col = v >> 3, ch = v & 7;
            int off = col * 128 + ((ch ^ (col & 7)) << 4);
            *(bf16x8*)(Bh + off) = gbh[jj];
            *(bf16x8*)(Bl + off) = gbl[jj];
        }
    };

    floatx4 acc[4][4];
    #pragma unroll
    for (int i = 0; i < 4; ++i)
        #pragma unroll
        for (int j = 0; j < 4; ++j) acc[i][j] = (floatx4){0.f, 0.f, 0.f, 0.f};

    float4 ga[8]; bf16x8 gbh[4], gbl[4];
    issue_loads(0, ga, gbh, gbl);
    write_lds(ga, gbh, gbl);

    for (int kt = 0; kt < 16; ++kt) {
        __syncthreads();
        if (kt < 15) issue_loads(kt + 1, ga, gbh, gbl);

        #pragma unroll
        for (int ks = 0; ks < 2; ++ks) {
            bf16x8 xh[4], xl[4], wh[4], wl[4];
            #pragma unroll
            for (int i = 0; i < 4; ++i) {
                int xrow = wm * 64 + i * 16 + c;
                int xoff = xrow * 128 + (((ks * 4 + q) ^ (xrow & 7)) << 4);
                xh[i] = *(const bf16x8*)(Ah + xoff);
                xl[i] = *(const bf16x8*)(Al + xoff);
                int wrow = wn * 64 + i * 16 + c;
                int woff = wrow * 128 + (((ks * 4 + q) ^ (wrow & 7)) << 4);
                wh[i] = *(const bf16x8*)(Bh + woff);
                wl[i] = *(const bf16x8*)(Bl + woff);
            }
            #pragma unroll
            for (int xi = 0; xi < 4; ++xi)
                #pragma unroll
                for (int ni = 0; ni < 4; ++ni) {
                    acc[xi][ni] = __builtin_amdgcn_mfma_f32_16x16x32_bf16(wh[ni], xh[xi], acc[xi][ni], 0, 0, 0);
                    acc[xi][ni] = __builtin_amdgcn_mfma_f32_16x16x32_bf16(wh[ni], xl[xi], acc[xi][ni], 0, 0, 0);
                    acc[xi][ni] = __builtin_amdgcn_mfma_f32_16x16x32_bf16(wl[ni], xh[xi], acc[xi][ni], 0, 0, 0);
                }
        }

        __syncthreads();
        if (kt < 15) write_lds(ga, gbh, gbl);
    }

    #pragma unroll
    for (int xi = 0; xi < 4; ++xi) {
        int tok = m0 + wm * 64 + xi * 16 + c;
        #pragma unroll
        for (int ni = 0; ni < 4; ++ni) {
            int nf4 = nb * 32 + wn * 16 + ni * 4 + q;
            float4 o;
            o.x = acc[xi][ni][0]; o.y = acc[xi][ni][1];
            o.z = acc[xi][ni][2]; o.w = acc[xi][ni][3];
            Zp[(size_t)tok * Z_F4 + nf4] = o;
        }
    }
}

// ---------------------------------------------------------------------------
// K1b: z = (z_pre + b) / (||z_pre + b|| + 1e-6) (unchanged)
// ---------------------------------------------------------------------------
__global__ __launch_bounds__(256) void k1b_norm(float4* __restrict__ Z,
                                                const float4* __restrict__ bias) {
    int wid = threadIdx.x >> 6, lane = threadIdx.x & 63;
    int t = blockIdx.x * 4 + wid;
    float4 b = bias[lane];
    float4 z = Z[(size_t)t * Z_F4 + lane];
    z.x += b.x; z.y += b.y; z.z += b.z; z.w += b.w;
    double ss = (double)z.x*z.x + (double)z.y*z.y + (double)z.z*z.z + (double)z.w*z.w;
    #pragma unroll
    for (int m = 32; m >= 1; m >>= 1) ss += __shfl_xor(ss, m, 64);
    float inv = 1.0f / ((float)sqrt(ss) + 1e-6f);
    z.x *= inv; z.y *= inv; z.z *= inv; z.w *= inv;
    Z[(size_t)t * Z_F4 + lane] = z;
}

// ---------------------------------------------------------------------------
// K2 v5b: v5 (LDS dbuf + counted vmcnt) + per-block tile PHASE stagger.
// v5 post-mortem: pipeline landed (LDS 72KB, VGPR 100) but dur ~unchanged;
// per-SIMD issue ~12% VALU / ~7% MFMA -> still latency-bound. Cause theory:
// all 512 blocks sweep the SAME 34KB codebook window in near-lockstep ->
// same-line L2 request fan-in (~64x per line per XCD) inflates latency past
// the 1-iteration prefetch cover. Fix: block walks tiles starting at phase
// (blockIdx>>3)&63 — the 64 blocks of each XCD (round-robin dispatch) get
// distinct phases, spreading requests over the whole 2.2MB codebook.
// Top-4 is order-independent; keys encode true tile id, so rotation is free.
// ---------------------------------------------------------------------------
__global__ __launch_bounds__(256, 2) void k2_mfma(const float* __restrict__ Z,
                                                  const ushort* __restrict__ Cbb2,
                                                  int4* __restrict__ cands) {
    __shared__ __align__(16) char sbuf[69632];   // [wc][2][17408]
    __shared__ uint32_t Mk[64][4][4];            // [token][wc*2+hi][rank]

    int tid  = threadIdx.x;
    int w    = tid >> 6;
    int wm   = w >> 1;           // token group / stage split
    int wc   = w & 1;            // code half
    int lane = tid & 63;
    int r    = lane & 31;
    int hi   = lane >> 5;
    int t0   = blockIdx.x * 64;
    int phase = (blockIdx.x >> 3) & 63;   // per-XCD distinct tile phase

    // ---- resident token fragments (B-operand): col=r, k = f*16 + hi*8 + j
    bf16x8 Bt[17];
    #pragma unroll
    for (int f = 0; f < 16; ++f) {
        const float* zp = Z + (size_t)(t0 + wm * 32 + r) * CD + f * 16 + hi * 8;
        float4 f0 = *(const float4*)zp;
        float4 f1 = *(const float4*)(zp + 4);
        bf16x8 b;
        b[0] = (short)f2bf(f0.x); b[1] = (short)f2bf(f0.y);
        b[2] = (short)f2bf(f0.z); b[3] = (short)f2bf(f0.w);
        b[4] = (short)f2bf(f1.x); b[5] = (short)f2bf(f1.y);
        b[6] = (short)f2bf(f1.z); b[7] = (short)f2bf(f1.w);
        Bt[f] = b;
    }
    {
        bf16x8 b = (bf16x8){0, 0, 0, 0, 0, 0, 0, 0};
        if (hi == 0) { b[0] = (short)0x3F80; b[1] = (short)0x3F80; }  // 1.0,1.0
        Bt[16] = b;
    }

    char* myStream = sbuf + wc * 34816;

    // stage my fragment range of global tile gt into LDS buffer dst.
    // per-lane global src; LDS dest = uniform base + lane*16 (HW).
    // gt==0: bump row-0 lanes (code 0) to row 1 (code 1) — clamp.
    auto stage = [&](int gt, char* dst) {
        const char* tb = (const char*)Cbb2 + (size_t)gt * TILE_B;
        int lo = lane * 16;
        if (gt == 0 && (lane & 31) == 0) lo += 16;
        if (wm == 0) {
            #pragma unroll
            for (int f = 0; f < 9; ++f)
                gload_lds16(tb + f * 1024 + lo, dst + f * 1024);
        } else {
            #pragma unroll
            for (int f = 9; f < 17; ++f)
                gload_lds16(tb + f * 1024 + lo, dst + f * 1024);
        }
    };

    float K1f = 0.0f, K2f = 0.0f, K3f = 0.0f, K4f = 0.0f;

    auto computeT = [&](const char* sb, int ct) {
        floatx16 Cc;
        #pragma unroll
        for (int i = 0; i < 16; ++i) Cc[i] = 0.0f;
        #pragma unroll
        for (int f = 0; f < 17; ++f) {
            bf16x8 Af = *(const bf16x8*)(sb + f * 1024 + lane * 16);
            Cc = __builtin_amdgcn_mfma_f32_32x32x16_bf16(Af, Bt[f], Cc, 0, 0, 0);
        }
        #pragma unroll
        for (int reg = 0; reg < 16; ++reg) {
            union { float f; uint32_t u; } uv; uv.f = Cc[reg];
            uint32_t ku = (uv.u & 0xFFFFF800u) | ((uint32_t)ct << 4) | (uint32_t)reg;
            union { uint32_t u; float f; } kv; kv.u = ku;
            float k = kv.f;
            K4f = __builtin_amdgcn_fmed3f(K3f, K4f, k);
            K3f = __builtin_amdgcn_fmed3f(K2f, K3f, k);
            K2f = __builtin_amdgcn_fmed3f(K1f, K2f, k);
            K1f = fmaxf(K1f, k);
        }
    };

    // prologue: stage tiles phase, phase+1 of my stream
    stage(wc * 64 + phase, myStream);
    stage(wc * 64 + ((phase + 1) & 63), myStream + 17408);

    for (int ctl = 0; ctl < 64; ++ctl) {
        int gtl = (ctl + phase) & 63;
        // wait own oldest stage (tile gtl) complete; partner covered by its
        // own wait + the barrier. Counts uniform across the loop.
        if (wm == 0) { asm volatile("s_waitcnt vmcnt(9)" ::: "memory"); }
        else         { asm volatile("s_waitcnt vmcnt(8)" ::: "memory"); }
        __builtin_amdgcn_s_barrier();

        computeT(myStream + (ctl & 1) * 17408, wc * 64 + gtl);

        __builtin_amdgcn_s_barrier();
        // refill the buffer just consumed with tile gtl+2 (wraps; uniform count)
        stage(wc * 64 + ((gtl + 2) & 63), myStream + (ctl & 1) * 17408);
    }

    // ---- merge: per token 4 sources (wc x hi) x top-4 -> global top-4
    {
        int lt = wm * 32 + r, src = wc * 2 + hi;
        union { float f; uint32_t u; } a, b, c, d;
        a.f = K1f; b.f = K2f; c.f = K3f; d.f = K4f;
        Mk[lt][src][0] = a.u; Mk[lt][src][1] = b.u;
        Mk[lt][src][2] = c.u; Mk[lt][src][3] = d.u;
    }
    __syncthreads();

    if (tid < 64) {
        uint32_t bk0 = 0, bk1 = 0, bk2 = 0, bk3 = 0;
        uint32_t be0 = 0, be1 = 0, be2 = 0, be3 = 0;
        #pragma unroll
        for (int s = 0; s < 4; ++s) {
            #pragma unroll
            for (int j = 0; j < 4; ++j) {
                uint32_t key = Mk[tid][s][j];
                uint32_t e = (uint32_t)s;           // hi = s&1
                if (key > bk0) {
                    bk3 = bk2; be3 = be2; bk2 = bk1; be2 = be1;
                    bk1 = bk0; be1 = be0; bk0 = key; be0 = e;
                } else if (key > bk1) {
                    bk3 = bk2; be3 = be2; bk2 = bk1; be2 = be1; bk1 = key; be1 = e;
                } else if (key > bk2) {
                    bk3 = bk2; be3 = be2; bk2 = key; be2 = e;
                } else if (key > bk3) {
                    bk3 = key; be3 = e;
                }
            }
        }
        auto dec = [&](uint32_t key, uint32_t e) -> int {
            int ct = (int)((key >> 4) & 127u);
            int rg = (int)(key & 15u);
            int row = (rg & 3) + 8 * (rg >> 2) + 4 * (int)(e & 1);
            int code = ct * 32 + row;
            return code < 1 ? 1 : code;
        };
        int4 out;
        out.x = dec(bk0, be0); out.y = dec(bk1, be1);
        out.z = dec(bk2, be2); out.w = dec(bk3, be3);
        cands[t0 + tid] = out;
    }
}

// ---------------------------------------------------------------------------
// K3: f64 re-rank of 4 candidates (code 0 invalid; ties -> lowest index),
// write index (as float) + gather hard code. One wave per token.
// ---------------------------------------------------------------------------
__global__ __launch_bounds__(256) void k3_refine(const float4* __restrict__ Z,
                                                 const float4* __restrict__ Cb,
                                                 const int4* __restrict__ cands,
                                                 float* __restrict__ idxOut,
                                                 float4* __restrict__ hardOut) {
    int wid = threadIdx.x >> 6, lane = threadIdx.x & 63;
    int t = blockIdx.x * 4 + wid;
    int4 cd = cands[t];
    int cc[4] = {cd.x, cd.y, cd.z, cd.w};
    float4 z = Z[(size_t)t * Z_F4 + lane];
    double best = -1.0e300;
    int bi = NC;   // sentinel
    #pragma unroll
    for (int e = 0; e < 4; ++e) {
        int idx = cc[e];
        float4 cf = Cb[(size_t)idx * C_F4 + lane];
        double dot = (double)z.x*cf.x + (double)z.y*cf.y + (double)z.z*cf.z + (double)z.w*cf.w;
        double nrm = (double)cf.x*cf.x + (double)cf.y*cf.y + (double)cf.z*cf.z + (double)cf.w*cf.w;
        #pragma unroll
        for (int m = 32; m >= 1; m >>= 1) {
            dot += __shfl_xor(dot, m, 64);
            nrm += __shfl_xor(nrm, m, 64);
        }
        double s = dot - 0.5 * nrm;
        if (idx >= 1 && (s > best || (s == best && idx < bi))) { best = s; bi = idx; }
    }
    if (lane == 0) idxOut[t] = (float)bi;
    hardOut[(size_t)t * C_F4 + lane] = Cb[(size_t)bi * C_F4 + lane];
}

// ---------------------------------------------------------------------------
extern "C" void kernel_launch(void* const* d_in, const int* in_sizes, int n_in,
                              void* d_out, int out_size, void* d_ws, size_t ws_size,
                              hipStream_t stream) {
    const float* x  = (const float*)d_in[0];   // 32768 x 1024
    const float* cb = (const float*)d_in[1];   // 4096 x 256
    const float* w  = (const float*)d_in[2];   // 1024 x 256
    const float* bd = (const float*)d_in[3];   // 256

    float* zOut    = (float*)d_out;                    // 32768 x 256
    float* idxOut  = zOut + (size_t)NT * CD;           // 32768 (as float values)
    float* hardOut = idxOut + NT;                      // 32768 x 256

    int4*   cands = (int4*)d_ws;                             // 512 KB
    ushort* cbb2  = (ushort*)((char*)d_ws + 524288);         // 128*17408 = 2,228,224 B
    ushort* wth   = (ushort*)((char*)d_ws + 2752512);        // 512 KB bf16 W^T hi
    ushort* wtl   = (ushort*)((char*)d_ws + 3276800);        // 512 KB bf16 W^T lo

    k0_prep<<<NC / 8, 256, 0, stream>>>((const float4*)cb, cbb2);
    k0b_wsplit<<<DM / 16, 256, 0, stream>>>((const float4*)w, wth, wtl);
    k1_gemm1<<<(NT / 128) * 2, 256, 0, stream>>>((const float4*)x, wth, wtl,
                                                 (float4*)zOut);
    k1b_norm<<<NT / 4, 256, 0, stream>>>((float4*)zOut, (const float4*)bd);
    k2_mfma<<<NT / 64, 256, 0, stream>>>(zOut, cbb2, cands);
    k3_refine<<<NT / 4, 256, 0, stream>>>((const float4*)zOut, (const float4*)cb,
                                          cands, idxOut, (float4*)hardOut);
}